// Round 5
// baseline (3216.566 us; speedup 1.0000x reference)
//
#include <hip/hip_runtime.h>
#include <math.h>

// Problem constants (match reference)
#define Hn   2560      // hidden units
#define Bn   64        // batch
#define INW  128       // input width
#define ETOT 2048      // total excitatory units (4 areas x 512)
#define HGn  160       // h-groups of 16
#define MAXC 13        // max 128-k chunks per h-group
#define NBLK 160       // grid size == HGn (co-resident: 160 <= 256 CUs @ 1 blk/CU)
#define MAXI 7         // max k-steps per wave: ceil(52/8)

typedef __attribute__((ext_vector_type(8))) _Float16 half8;  // 8 f16 = 4 VGPRs
typedef __attribute__((ext_vector_type(4))) float  floatx4;  // MFMA acc / NT store

// ---------------------------------------------------------------------------
// Prep: masked signed W -> MFMA A-fragments, split hi/lo f16 (W to 2^-22 rel).
// Af[(hg*13+c)] = 4 kq x {hi,lo} x 64 lanes x 8 f16 (8 KB per 128-k chunk).
// A[m][k]: m = lane&15, k = (lane>>4)*8 + j.   (unchanged)
// ---------------------------------------------------------------------------
__global__ void build_apack(const float* __restrict__ Wrec,
                            const float* __restrict__ Win,
                            _Float16* __restrict__ Af) {
  int hg = blockIdx.x, c = blockIdx.y;
  int a = (hg < 128) ? (hg >> 5) : ((hg - 128) >> 3);
  int nE = (a == 0 || a == 3) ? 8 : 12;
  int nch = nE + 1 + (a == 0 ? 1 : 0);
  if (c >= nch) return;
  int h0 = hg * 16;
  int tid = threadIdx.x;
  int kq = tid >> 6, L = tid & 63;
  int m = L & 15, q = L >> 4;
  int h = h0 + m;

  const float* src; int k0, stride; float sgn; bool isIn = false;
  if (c < nE)       { k0 = ((a == 0 ? 0 : a - 1) << 9) + (c << 7); src = Wrec; stride = Hn;  sgn =  1.f; }
  else if (c == nE) { k0 = ETOT + (a << 7);                        src = Wrec; stride = Hn;  sgn = -1.f; }
  else              { k0 = 0;                                      src = Win;  stride = INW; sgn =  1.f; isIn = true; }

  _Float16 hi8[8], lo8[8];
  #pragma unroll
  for (int j = 0; j < 8; ++j) {
    int k = k0 + kq * 32 + q * 8 + j;
    float w = fabsf(src[(size_t)h * stride + k]);
    if (!isIn && k == h) w = 0.f;     // remove_diag
    w *= sgn;
    _Float16 wh = (_Float16)w;
    hi8[j] = wh;
    lo8[j] = (_Float16)(w - (float)wh);
  }
  _Float16* outp = Af + (size_t)(hg * MAXC + c) * 4096;
  *(uint4*)(outp + (kq * 2 + 0) * 512 + L * 8) = *(const uint4*)hi8;
  *(uint4*)(outp + (kq * 2 + 1) * 512 + L * 8) = *(const uint4*)lo8;
}

// ---- LLC-coherent (sc0 sc1) rf loads: ISSUE ONLY, no wait. A single
// vmcnt(0)+sched_barrier(0) later fences all of them at once (rule 18).
#define LOADI(B0,B1,B2,B3,P) \
  asm volatile("global_load_dwordx4 %0, %4, off sc0 sc1\n\t" \
               "global_load_dwordx4 %1, %4, off offset:1024 sc0 sc1\n\t" \
               "global_load_dwordx4 %2, %4, off offset:2048 sc0 sc1\n\t" \
               "global_load_dwordx4 %3, %4, off offset:3072 sc0 sc1" \
               : "=&v"(B0), "=&v"(B1), "=&v"(B2), "=&v"(B3) \
               : "v"(P) : "memory")

#define MFMA8(i, B0,B1,B2,B3) do { \
  ac0 = __builtin_amdgcn_mfma_f32_16x16x32_f16(ah[i], B0, ac0, 0, 0, 0); \
  ac0 = __builtin_amdgcn_mfma_f32_16x16x32_f16(al[i], B0, ac0, 0, 0, 0); \
  ac1 = __builtin_amdgcn_mfma_f32_16x16x32_f16(ah[i], B1, ac1, 0, 0, 0); \
  ac1 = __builtin_amdgcn_mfma_f32_16x16x32_f16(al[i], B1, ac1, 0, 0, 0); \
  ac2 = __builtin_amdgcn_mfma_f32_16x16x32_f16(ah[i], B2, ac2, 0, 0, 0); \
  ac2 = __builtin_amdgcn_mfma_f32_16x16x32_f16(al[i], B2, ac2, 0, 0, 0); \
  ac3 = __builtin_amdgcn_mfma_f32_16x16x32_f16(ah[i], B3, ac3, 0, 0, 0); \
  ac3 = __builtin_amdgcn_mfma_f32_16x16x32_f16(al[i], B3, ac3, 0, 0, 0); \
} while (0)

// ---------------------------------------------------------------------------
// Persistent kernel, fence-free coherence (R4-proven), latency-collapsed:
//  - launch_bounds(512,1): 256-VGPR budget (160 blks <= 256 CUs -> 1 blk/CU
//    regardless; occupancy unchanged, VGPR headroom unlocked).
//  - ALL rec-chunk sc0sc1 loads issued up front (<=28 dwordx4 in flight),
//    ONE vmcnt(0) + sched_barrier(0), then all MFMAs: one exposed MALL
//    latency per step instead of 3-4 (R4: serialized PAIR waits).
//  - barrier: poll the master counter directly (gen-flag hop removed).
//  - A-frags pinned in VGPRs; x in regs; rates nontemporal.
// ---------------------------------------------------------------------------
__global__ __launch_bounds__(512, 1) void rnn_persist(
    const _Float16* __restrict__ Af,
    const float* __restrict__ inputs,
    _Float16* __restrict__ rfA, _Float16* __restrict__ rfB,
    const float* __restrict__ brec,
    float* __restrict__ rates,
    unsigned* bar, int T)
{
  __shared__ float red[8][1056];     // 8 wave-partials, 16 x 66-padded
  __shared__ float rrt[16][68];      // rates staging (padded)
  __shared__ float bb[16];

  const int hg  = blockIdx.x;
  const int tid = threadIdx.x;
  const int w   = tid >> 6, L = tid & 63;
  const int h0  = hg * 16;
  const int a   = (hg < 128) ? (hg >> 5) : ((hg - 128) >> 3);
  const int nE  = (a == 0 || a == 3) ? 8 : 12;
  const int SK  = (nE + 1 + (a == 0 ? 1 : 0)) * 4;   // 40 / 52 / 52 / 36
  const int ktE0 = (a == 0 ? 0 : a - 1) * 16;
  const int ktI0 = 64 + a * 4;

  unsigned* bsub = bar + (hg & 7) * 64;   // 8 sub-counters, 256B apart
  unsigned* bmas = bar + 8 * 64;          // master: +1 per completed sub-group

  if (tid < 16) bb[tid] = brec[h0 + tid];

  // ---- one-time A preload + pin in VGPRs ----
  half8 ah[MAXI], al[MAXI];
  int   boff[MAXI];
  bool  act[MAXI], isin[MAXI];
  const _Float16* Abase = Af + (size_t)hg * MAXC * 4096;
  #pragma unroll
  for (int i = 0; i < MAXI; ++i) {
    half8 zz = {0,0,0,0,0,0,0,0};
    ah[i] = zz; al[i] = zz;
    int ks = w + i * 8;
    act[i]  = ks < SK;
    isin[i] = false;
    boff[i] = 0;
    if (act[i]) {
      int c = ks >> 2, kq = ks & 3;
      const _Float16* Ap = Abase + (size_t)c * 4096 + (size_t)(kq * 2) * 512 + (size_t)L * 8;
      ah[i] = *(const half8*)Ap;
      al[i] = *(const half8*)(Ap + 512);
      if (c <= nE) {           // recurrent chunk: rf offset (half units)
        int kt = (c < nE) ? (ktE0 + c * 4 + kq) : (ktI0 + kq);
        boff[i] = kt * 2048 + L * 8;
      } else {                 // input chunk (area 0): inputs offset base
        isin[i] = true;
        boff[i] = kq * 32 + (L >> 4) * 8;
      }
    }
  }
  // opaque pin: values now "produced" by asm -> cannot be rematerialized
  #pragma unroll
  for (int i = 0; i < MAXI; ++i)
    asm volatile("" : "+v"(ah[i]), "+v"(al[i]));

  float xv[2] = {0.f, 0.f};    // x state: 2 elems/thread, lives in regs

  __syncthreads();             // bb ready

  for (int t = 0; t < T; ++t) {
    const _Float16* __restrict__ rs = (t & 1) ? rfB : rfA;
    _Float16* __restrict__ rd       = (t & 1) ? rfA : rfB;

    floatx4 ac0 = {0.f,0.f,0.f,0.f}, ac1 = {0.f,0.f,0.f,0.f};
    floatx4 ac2 = {0.f,0.f,0.f,0.f}, ac3 = {0.f,0.f,0.f,0.f};

    // -- input chunk first (compiler-managed cached loads; its waitcnts
    //    then can't over-drain the asm rec loads issued below) --
    #pragma unroll
    for (int i = 0; i < MAXI; ++i) {
      if (act[i] && isin[i]) {                     // wave-uniform
        const float* ip = inputs + (size_t)t * (Bn * INW) + boff[i];
        int nb = L & 15;
        half8 b0, b1, b2, b3;
        #pragma unroll
        for (int j = 0; j < 8; ++j) b0[j] = (_Float16)ip[(nb +  0) * INW + j];
        #pragma unroll
        for (int j = 0; j < 8; ++j) b1[j] = (_Float16)ip[(nb + 16) * INW + j];
        #pragma unroll
        for (int j = 0; j < 8; ++j) b2[j] = (_Float16)ip[(nb + 32) * INW + j];
        #pragma unroll
        for (int j = 0; j < 8; ++j) b3[j] = (_Float16)ip[(nb + 48) * INW + j];
        MFMA8(i, b0, b1, b2, b3);
      }
    }

    // -- issue ALL rec loads (<=28 dwordx4 in flight to the MALL) --
    half8 Bv0[MAXI], Bv1[MAXI], Bv2[MAXI], Bv3[MAXI];   // static-indexed only
    #pragma unroll
    for (int i = 0; i < MAXI; ++i) {
      if (act[i] && !isin[i]) {
        const _Float16* p = rs + boff[i];
        LOADI(Bv0[i], Bv1[i], Bv2[i], Bv3[i], p);
      }
    }
    // single drain + scheduling fence (keeps MFMAs below the wait: rule 18)
    asm volatile("s_waitcnt vmcnt(0)" ::: "memory");
    __builtin_amdgcn_sched_barrier(0);

    #pragma unroll
    for (int i = 0; i < MAXI; ++i) {
      if (act[i] && !isin[i])
        MFMA8(i, Bv0[i], Bv1[i], Bv2[i], Bv3[i]);
    }

    // dump split-k partials to LDS
    #pragma unroll
    for (int p = 0; p < 4; ++p) {
      int m = (L >> 4) * 4 + p;
      float* rw = &red[w][m * 66 + (L & 15)];
      rw[ 0] = ac0[p];
      rw[16] = ac1[p];
      rw[32] = ac2[p];
      rw[48] = ac3[p];
    }
    __syncthreads();

    // reduce 8 partials + bias + leaky-integrate + retanh (2 elems/thread)
    #pragma unroll
    for (int e = 0; e < 2; ++e) {
      int elem = tid + e * 512;
      int m = elem >> 6, n = elem & 63;
      float s = 0.f;
      #pragma unroll
      for (int j = 0; j < 8; ++j) s += red[j][m * 66 + n];
      float x = 0.8f * xv[e] + 0.2f * (s + bb[m]);   // ALPHA_X = 0.2
      xv[e] = x;
      rrt[m][n] = tanhf(fmaxf(x, 0.f));
    }
    __syncthreads();

    // tid<128: emit next-step r B-fragments via MALL-coherent stores.
    // vmcnt(0) inside the asm: store is at the LLC before barrier arrival.
    if (tid < 128) {
      int bt = tid >> 5, Lq = tid & 31;
      int Lp = (hg & 1) * 32 + Lq;
      half8 vv;
      #pragma unroll
      for (int j = 0; j < 8; ++j)
        vv[j] = (_Float16)rrt[(Lq >> 4) * 8 + j][bt * 16 + (Lq & 15)];
      _Float16* dst = rd + (size_t)((hg >> 1) * 4 + bt) * 512 + (size_t)Lp * 8;
      asm volatile("global_store_dwordx4 %0, %1, off sc0 sc1\n\t"
                   "s_waitcnt vmcnt(0)"
                   :: "v"(dst), "v"(vv) : "memory");
    }
    // tid in [256,512): rates[t][b][h0..h0+15], nontemporal (don't pollute MALL)
    if (tid >= 256) {
      int tt = tid - 256;
      int b = tt >> 2, hq = tt & 3;
      floatx4 o;
      o.x = rrt[hq * 4 + 0][b];
      o.y = rrt[hq * 4 + 1][b];
      o.z = rrt[hq * 4 + 2][b];
      o.w = rrt[hq * 4 + 3][b];
      __builtin_nontemporal_store(o,
          (floatx4*)(rates + (size_t)t * (Bn * Hn) + (size_t)b * Hn + h0 + hq * 4));
    }
    __syncthreads();   // all waves' rf stores complete (asm-internal vmcnt 0)

    // ---- device barrier: relaxed agent atomics, poll master directly ----
    // causality: each sub fetch_add RETURNS before the (conditional) master
    // add is issued, so master==8g implies all 160 rf-store sets are at LLC.
    if (t + 1 < T) {
      if (tid == 0) {
        unsigned g = (unsigned)(t + 1);
        unsigned s = __hip_atomic_fetch_add(bsub, 1u, __ATOMIC_RELAXED,
                                            __HIP_MEMORY_SCOPE_AGENT);
        if (s == g * 20u - 1u)
          __hip_atomic_fetch_add(bmas, 1u, __ATOMIC_RELAXED,
                                 __HIP_MEMORY_SCOPE_AGENT);
        while (__hip_atomic_load(bmas, __ATOMIC_RELAXED,
                                 __HIP_MEMORY_SCOPE_AGENT) < g * 8u)
          __builtin_amdgcn_s_sleep(2);
      }
      __syncthreads();   // block released; next rf reads are sc0sc1 (fresh)
    }
  }
}

// ---------------------------------------------------------------------------
extern "C" void kernel_launch(void* const* d_in, const int* in_sizes, int n_in,
                              void* d_out, int out_size, void* d_ws, size_t ws_size,
                              hipStream_t stream) {
  const float* inputs = (const float*)d_in[0];   // [T, 64, 128]
  const float* Wrec   = (const float*)d_in[1];   // [2560, 2560]
  const float* brec   = (const float*)d_in[2];   // [2560]
  const float* Win    = (const float*)d_in[3];   // [2560, 128]
  int T = in_sizes[0] / (Bn * INW);              // 500

  char* base = (char*)d_ws;
  size_t off = 0;
  _Float16* Af  = (_Float16*)(base + off); off += (size_t)HGn * MAXC * 4096 * 2;  // 17.0 MB
  _Float16* rfA = (_Float16*)(base + off); off += (size_t)80 * 4 * 512 * 2;       // 320 KB
  _Float16* rfB = (_Float16*)(base + off); off += (size_t)80 * 4 * 512 * 2;       // 320 KB
  unsigned* bar = (unsigned*)(base + off); off += 4096;                           // barrier state

  // r0 = retanh(0) = 0 (f16 zero == 0x0000); ws poisoned each call, so rfA
  // and the barrier counters must be re-zeroed every launch.
  (void)hipMemsetAsync(rfA, 0, (size_t)80 * 4 * 512 * 2, stream);
  (void)hipMemsetAsync(bar, 0, 4096, stream);

  build_apack<<<dim3(HGn, MAXC), 256, 0, stream>>>(Wrec, Win, Af);

  float* rates = (float*)d_out;
  rnn_persist<<<NBLK, 512, 0, stream>>>(Af, inputs, rfA, rfB, brec, rates,
                                        bar, T);
}